// Round 1
// baseline (28326.599 us; speedup 1.0000x reference)
//
#include <hip/hip_runtime.h>

// LSTM_63402307223694 — Round 1: fp32 correctness-first baseline.
// B=64, T=256, D_IN=256, H=1024, D_OUT=1, 3 layers, gate order i,f,g,o.
//
// Structure:
//   - transpose w_ih/w_hh into [K, 4H] (coalesced weight reads)
//   - bias[l] = b_ih[l] + b_hh[l]
//   - per layer, in T-chunks of 64: proj_gemm (xg = in @ w_ih^T + bias),
//     then 64x lstm_step (one launch per timestep; h double-buffered)
//   - final_fc: out[b] = h_seq[T-1,b,:] . fc_w + fc_b
//
// Workspace budget (~213 MB): 5x16MB + 4MB transposed weights, 48KB bias,
// 3x256KB h/c buffers, 64MB h_seq, 64MB xg chunk.

#define BB 64
#define TT 256
#define DIN 256
#define HH 1024
#define G4 4096
#define TCHUNK 64

// ---------------- transpose: src[R,C] -> dst[C,R], R,C multiples of 32 ----
__global__ __launch_bounds__(256) void transpose_f32(
    const float* __restrict__ src, float* __restrict__ dst, int R, int C) {
  __shared__ float tile[32][33];
  int c0 = blockIdx.x * 32, r0 = blockIdx.y * 32;
  int tx = threadIdx.x & 31, ty = threadIdx.x >> 5;  // ty 0..7
#pragma unroll
  for (int i = 0; i < 32; i += 8) {
    tile[ty + i][tx] = src[(size_t)(r0 + ty + i) * C + (c0 + tx)];
  }
  __syncthreads();
#pragma unroll
  for (int i = 0; i < 32; i += 8) {
    dst[(size_t)(c0 + ty + i) * R + (r0 + tx)] = tile[tx][ty + i];
  }
}

// ---------------- bias combine ----------------
__global__ __launch_bounds__(256) void bias_add(
    const float* __restrict__ a, const float* __restrict__ b,
    float* __restrict__ o) {
  int i = blockIdx.x * 256 + threadIdx.x;  // grid 16 -> 4096
  o[i] = a[i] + b[i];
}

// ---------------- projection GEMM ----------------
// xg_chunk[m_local, n] = bias[n] + sum_k A[m,k] * Wt[k,n]
// m_global = t_base*64 + m_local ; t = m_global/64, b = m_global%64
// layer0: A row = x + b*65536 + t*256 (reshape [B,T,DIN] of [B,DIN*T] flat)
// layer>=1: A row = h_seq + m_global*1024
__global__ __launch_bounds__(256) void proj_gemm(
    const float* __restrict__ A, const float* __restrict__ Wt,
    const float* __restrict__ bias, float* __restrict__ xg,
    int K, int is_l0, int t_base) {
  __shared__ float As[16][68];
  __shared__ float Bs[16][64];
  const int n0 = blockIdx.x * 64;  // grid.x = 64
  const int m0 = blockIdx.y * 64;  // grid.y = 64 (4096 rows per chunk)
  const int tid = threadIdx.x;
  const int tni = tid & 15, tmi = tid >> 4;
  float acc[4][4] = {};
  for (int k0 = 0; k0 < K; k0 += 16) {
#pragma unroll
    for (int i = 0; i < 4; ++i) {
      int idx = i * 256 + tid;
      int mm = idx >> 4, kk = idx & 15;
      int mrow = m0 + mm;
      const float* arow;
      if (is_l0) {
        int mg = t_base * 64 + mrow;
        int b = mg & 63, t = mg >> 6;
        arow = A + (size_t)b * (DIN * TT) + (size_t)t * DIN;
      } else {
        arow = A + ((size_t)t_base * 64 + mrow) * HH;
      }
      As[kk][mm] = arow[k0 + kk];
    }
#pragma unroll
    for (int i = 0; i < 4; ++i) {
      int idx = i * 256 + tid;
      int kk = idx >> 6, nn = idx & 63;
      Bs[kk][nn] = Wt[(size_t)(k0 + kk) * G4 + n0 + nn];
    }
    __syncthreads();
#pragma unroll
    for (int kk = 0; kk < 16; ++kk) {
      float4 a4 = *(const float4*)&As[kk][tmi * 4];
      float4 b4 = *(const float4*)&Bs[kk][tni * 4];
      float av[4] = {a4.x, a4.y, a4.z, a4.w};
      float bv[4] = {b4.x, b4.y, b4.z, b4.w};
#pragma unroll
      for (int i = 0; i < 4; ++i)
#pragma unroll
        for (int j = 0; j < 4; ++j) acc[i][j] += av[i] * bv[j];
    }
    __syncthreads();
  }
  float4 bb4 = *(const float4*)&bias[n0 + tni * 4];
  float bv[4] = {bb4.x, bb4.y, bb4.z, bb4.w};
#pragma unroll
  for (int i = 0; i < 4; ++i) {
    int m = m0 + tmi * 4 + i;
    float4 o;
    o.x = acc[i][0] + bv[0];
    o.y = acc[i][1] + bv[1];
    o.z = acc[i][2] + bv[2];
    o.w = acc[i][3] + bv[3];
    *(float4*)&xg[(size_t)m * G4 + n0 + tni * 4] = o;
  }
}

// ---------------- one LSTM timestep ----------------
// grid (32 j-tiles, 8 b-tiles), 256 threads.
// Block tile: 32 hidden units x 8 batches. Thread: one float4 of one gate.
__global__ __launch_bounds__(256) void lstm_step(
    const float* __restrict__ xg,    // chunk [64, B, 4H]
    const float* __restrict__ Wt,    // [1024, 4096] transposed w_hh
    const float* __restrict__ h_in,  // [B, H]
    float* __restrict__ h_out,       // [B, H]
    float* __restrict__ c_cur,       // [B, H] (read+write)
    float* __restrict__ h_seq,       // [T, B, H]
    int t) {
  __shared__ float h_lds[8 * 1028];          // 8 rows, pad 1028
  __shared__ float gates[8 * 32 * 4];        // [bl][jl][g]
  const int tid = threadIdx.x;
  const int j0 = blockIdx.x * 32;            // 0..31 tiles
  const int b0 = blockIdx.y * 8;             // 0..7 tiles
  // stage h_in tile: 8 rows x 1024 = 2048 float4, 8 per thread
#pragma unroll
  for (int i = 0; i < 8; ++i) {
    int idx = i * 256 + tid;                 // float4 index
    int row = idx >> 8, c4 = idx & 255;
    *(float4*)&h_lds[row * 1028 + c4 * 4] =
        *(const float4*)&h_in[(size_t)(b0 + row) * HH + c4 * 4];
  }
  __syncthreads();
  const int q = tid & 7;             // j quad: j = j0 + q*4
  const int g = (tid >> 3) & 3;      // gate
  const int bl = tid >> 5;           // local batch 0..7
  const int b = b0 + bl;
  const float* wp = Wt + (size_t)g * HH + j0 + q * 4;
  const int tl = t & (TCHUNK - 1);
  float4 acc = *(const float4*)&xg[((size_t)tl * BB + b) * G4 + (size_t)g * HH + j0 + q * 4];
  const float* hp = &h_lds[bl * 1028];
#pragma unroll 8
  for (int k = 0; k < HH; ++k) {
    float hk = hp[k];
    float4 w = *(const float4*)&wp[(size_t)k * G4];
    acc.x += hk * w.x;
    acc.y += hk * w.y;
    acc.z += hk * w.z;
    acc.w += hk * w.w;
  }
  // exchange gates through LDS: gates[(bl*32 + jl)*4 + g]
  gates[(bl * 32 + q * 4 + 0) * 4 + g] = acc.x;
  gates[(bl * 32 + q * 4 + 1) * 4 + g] = acc.y;
  gates[(bl * 32 + q * 4 + 2) * 4 + g] = acc.z;
  gates[(bl * 32 + q * 4 + 3) * 4 + g] = acc.w;
  __syncthreads();
  {
    int bl2 = tid >> 5, jl2 = tid & 31;
    float4 gv = *(const float4*)&gates[(bl2 * 32 + jl2) * 4];  // i,f,g,o
    int bb = b0 + bl2, jj = j0 + jl2;
    size_t hidx = (size_t)bb * HH + jj;
    float cprev = c_cur[hidx];
    float ig = 1.f / (1.f + __expf(-gv.x));
    float fg = 1.f / (1.f + __expf(-gv.y));
    float gg = tanhf(gv.z);
    float og = 1.f / (1.f + __expf(-gv.w));
    float cn = fg * cprev + ig * gg;
    float hn = og * tanhf(cn);
    c_cur[hidx] = cn;
    h_out[hidx] = hn;
    h_seq[((size_t)t * BB + bb) * HH + jj] = hn;
  }
}

// ---------------- final FC: out[b] = h_seq[T-1,b,:] . fc_w + fc_b --------
__global__ __launch_bounds__(256) void final_fc(
    const float* __restrict__ h_seq, const float* __restrict__ fc_w,
    const float* __restrict__ fc_b, float* __restrict__ out) {
  int b = blockIdx.x;
  const float* hrow = h_seq + ((size_t)(TT - 1) * BB + b) * HH;
  float s = 0.f;
  for (int j = threadIdx.x; j < HH; j += 256) s += hrow[j] * fc_w[j];
#pragma unroll
  for (int off = 32; off > 0; off >>= 1) s += __shfl_down(s, off, 64);
  __shared__ float wsum[4];
  int wv = threadIdx.x >> 6, ln = threadIdx.x & 63;
  if (ln == 0) wsum[wv] = s;
  __syncthreads();
  if (threadIdx.x == 0) out[b] = wsum[0] + wsum[1] + wsum[2] + wsum[3] + fc_b[0];
}

extern "C" void kernel_launch(void* const* d_in, const int* in_sizes, int n_in,
                              void* d_out, int out_size, void* d_ws,
                              size_t ws_size, hipStream_t stream) {
  const float* x = (const float*)d_in[0];
  const float* w_ih[3] = {(const float*)d_in[1], (const float*)d_in[5],
                          (const float*)d_in[9]};
  const float* w_hh[3] = {(const float*)d_in[2], (const float*)d_in[6],
                          (const float*)d_in[10]};
  const float* b_ih[3] = {(const float*)d_in[3], (const float*)d_in[7],
                          (const float*)d_in[11]};
  const float* b_hh[3] = {(const float*)d_in[4], (const float*)d_in[8],
                          (const float*)d_in[12]};
  const float* fc_w = (const float*)d_in[13];
  const float* fc_b = (const float*)d_in[14];
  float* out = (float*)d_out;

  char* ws = (char*)d_ws;
  size_t off = 0;
  auto alloc = [&](size_t bytes) {
    float* p = (float*)(ws + off);
    off += bytes;
    return p;
  };
  float* wt_ih[3];
  wt_ih[0] = alloc((size_t)DIN * G4 * 4);
  wt_ih[1] = alloc((size_t)HH * G4 * 4);
  wt_ih[2] = alloc((size_t)HH * G4 * 4);
  float* wt_hh[3];
  for (int l = 0; l < 3; ++l) wt_hh[l] = alloc((size_t)HH * G4 * 4);
  float* bias[3];
  for (int l = 0; l < 3; ++l) bias[l] = alloc((size_t)G4 * 4);
  float* h_a = alloc((size_t)BB * HH * 4);
  float* h_b = alloc((size_t)BB * HH * 4);
  float* c0 = alloc((size_t)BB * HH * 4);
  float* hseq = alloc((size_t)TT * BB * HH * 4);
  float* xg = alloc((size_t)TCHUNK * BB * G4 * 4);
  // total ~213 MB

  // transposes: w_ih0 [4096,256] -> [256,4096]; others [4096,1024] -> [1024,4096]
  transpose_f32<<<dim3(DIN / 32, G4 / 32), 256, 0, stream>>>(w_ih[0], wt_ih[0], G4, DIN);
  transpose_f32<<<dim3(HH / 32, G4 / 32), 256, 0, stream>>>(w_ih[1], wt_ih[1], G4, HH);
  transpose_f32<<<dim3(HH / 32, G4 / 32), 256, 0, stream>>>(w_ih[2], wt_ih[2], G4, HH);
  for (int l = 0; l < 3; ++l)
    transpose_f32<<<dim3(HH / 32, G4 / 32), 256, 0, stream>>>(w_hh[l], wt_hh[l], G4, HH);
  for (int l = 0; l < 3; ++l)
    bias_add<<<16, 256, 0, stream>>>(b_ih[l], b_hh[l], bias[l]);

  for (int l = 0; l < 3; ++l) {
    hipMemsetAsync(h_a, 0, (size_t)BB * HH * 4, stream);
    hipMemsetAsync(c0, 0, (size_t)BB * HH * 4, stream);
    int K = (l == 0) ? DIN : HH;
    const float* A = (l == 0) ? x : hseq;
    for (int c = 0; c < TT / TCHUNK; ++c) {
      proj_gemm<<<dim3(G4 / 64, TCHUNK * BB / 64), 256, 0, stream>>>(
          A, wt_ih[l], bias[l], xg, K, (l == 0) ? 1 : 0, c * TCHUNK);
      for (int tt = 0; tt < TCHUNK; ++tt) {
        int t = c * TCHUNK + tt;
        float* hin = (t & 1) ? h_b : h_a;
        float* hout = (t & 1) ? h_a : h_b;
        lstm_step<<<dim3(HH / 32, BB / 8), 256, 0, stream>>>(
            xg, wt_hh[l], hin, hout, c0, hseq, t);
      }
    }
  }
  final_fc<<<BB, 256, 0, stream>>>(hseq, fc_w, fc_b, out);
}

// Round 2
// 28099.054 us; speedup vs baseline: 1.0081x; 1.0081x over previous
//
#include <hip/hip_runtime.h>

// LSTM_63402307223694 — Round 2: fp32, restructured step + bigger proj tiles.
// B=64, T=256, D_IN=256, H=1024, D_OUT=1, 3 layers, gate order i,f,g,o.
//
// lstm_step2: grid 256 blocks (64 j-tiles x 4 b-tiles), block 256 thr.
//   Wave lanes = 16 j x 4 gates; wave handles 4 batches (4 accs/lane).
//   h_in tile (16 batches, 64KB) in LDS, read as broadcast float4.
//   Weights streamed from ORIGINAL w_hh [4H][H] layout (contiguous along k).
//   Gate exchange via 16 __shfl, pointwise in-kernel.
// proj_gemm2: 128x128 tile, 8x8 micro-tile, k-tile 16, 1024 blocks/chunk.

#define BB 64
#define TT 256
#define DIN 256
#define HH 1024
#define G4 4096
#define TCHUNK 64

// ---------------- transpose: src[R,C] -> dst[C,R] (w_ih only) ----
__global__ __launch_bounds__(256) void transpose_f32(
    const float* __restrict__ src, float* __restrict__ dst, int R, int C) {
  __shared__ float tile[32][33];
  int c0 = blockIdx.x * 32, r0 = blockIdx.y * 32;
  int tx = threadIdx.x & 31, ty = threadIdx.x >> 5;
#pragma unroll
  for (int i = 0; i < 32; i += 8)
    tile[ty + i][tx] = src[(size_t)(r0 + ty + i) * C + (c0 + tx)];
  __syncthreads();
#pragma unroll
  for (int i = 0; i < 32; i += 8)
    dst[(size_t)(c0 + ty + i) * R + (r0 + tx)] = tile[tx][ty + i];
}

__global__ __launch_bounds__(256) void bias_add(
    const float* __restrict__ a, const float* __restrict__ b,
    float* __restrict__ o) {
  int i = blockIdx.x * 256 + threadIdx.x;
  o[i] = a[i] + b[i];
}

// ---------------- projection GEMM v2: 128x128, 8x8/thread ----------------
// xg[m, n] = bias[n] + sum_k A[m,k] * Wt[k,n]   (m local to 4096-row chunk)
__global__ __launch_bounds__(256) void proj_gemm2(
    const float* __restrict__ A, const float* __restrict__ Wt,
    const float* __restrict__ bias, float* __restrict__ xg,
    int K, int is_l0, int t_base) {
  __shared__ float As[16][132];
  __shared__ float Bs[16][132];
  const int n0 = blockIdx.x * 128;  // grid.x = 32
  const int m0 = blockIdx.y * 128;  // grid.y = 32
  const int tid = threadIdx.x;
  const int tn = tid & 15, tm = tid >> 4;  // 16 x 16 threads, 8x8 each
  float acc[8][8] = {};
  for (int k0 = 0; k0 < K; k0 += 16) {
    // stage A (transposed to As[k][m]) : 128 m x 16 k
#pragma unroll
    for (int i = 0; i < 2; ++i) {
      int fidx = i * 256 + tid;  // 0..511 float4 loads
      int m = fidx >> 2, kq = fidx & 3;
      int mrow = m0 + m;
      const float* arow;
      if (is_l0) {
        int mg = t_base * 64 + mrow;
        int b = mg & 63, t = mg >> 6;
        arow = A + (size_t)b * (DIN * TT) + (size_t)t * DIN;
      } else {
        arow = A + ((size_t)t_base * 64 + mrow) * HH;
      }
      float4 av = *(const float4*)&arow[k0 + kq * 4];
      As[kq * 4 + 0][m] = av.x;
      As[kq * 4 + 1][m] = av.y;
      As[kq * 4 + 2][m] = av.z;
      As[kq * 4 + 3][m] = av.w;
    }
    // stage B: 16 k x 128 n
#pragma unroll
    for (int i = 0; i < 2; ++i) {
      int fidx = i * 256 + tid;
      int kk = fidx >> 5, nq = fidx & 31;
      *(float4*)&Bs[kk][nq * 4] =
          *(const float4*)&Wt[(size_t)(k0 + kk) * G4 + n0 + nq * 4];
    }
    __syncthreads();
#pragma unroll
    for (int kk = 0; kk < 16; ++kk) {
      float4 a0 = *(const float4*)&As[kk][tm * 8];
      float4 a1 = *(const float4*)&As[kk][tm * 8 + 4];
      float4 b0 = *(const float4*)&Bs[kk][tn * 8];
      float4 b1 = *(const float4*)&Bs[kk][tn * 8 + 4];
      float av[8] = {a0.x, a0.y, a0.z, a0.w, a1.x, a1.y, a1.z, a1.w};
      float bv[8] = {b0.x, b0.y, b0.z, b0.w, b1.x, b1.y, b1.z, b1.w};
#pragma unroll
      for (int i = 0; i < 8; ++i)
#pragma unroll
        for (int j = 0; j < 8; ++j) acc[i][j] = fmaf(av[i], bv[j], acc[i][j]);
    }
    __syncthreads();
  }
  float4 bb0 = *(const float4*)&bias[n0 + tn * 8];
  float4 bb1 = *(const float4*)&bias[n0 + tn * 8 + 4];
  float bv[8] = {bb0.x, bb0.y, bb0.z, bb0.w, bb1.x, bb1.y, bb1.z, bb1.w};
#pragma unroll
  for (int r = 0; r < 8; ++r) {
    int m = m0 + tm * 8 + r;
    float4 o0, o1;
    o0.x = acc[r][0] + bv[0]; o0.y = acc[r][1] + bv[1];
    o0.z = acc[r][2] + bv[2]; o0.w = acc[r][3] + bv[3];
    o1.x = acc[r][4] + bv[4]; o1.y = acc[r][5] + bv[5];
    o1.z = acc[r][6] + bv[6]; o1.w = acc[r][7] + bv[7];
    *(float4*)&xg[(size_t)m * G4 + n0 + tn * 8] = o0;
    *(float4*)&xg[(size_t)m * G4 + n0 + tn * 8 + 4] = o1;
  }
}

// ---------------- one LSTM timestep, v2 ----------------
// grid (64 j-tiles, 4 b-tiles), 256 threads = 4 waves.
// Lane (of 64): g = lane>>4 (gate), jl = lane&15 (hidden j within tile).
// Wave w handles batches b0 + 4w .. +3 (one acc each).
__global__ __launch_bounds__(256) void lstm_step2(
    const float* __restrict__ xg,    // chunk [64, B, 4H]
    const float* __restrict__ w_hh,  // ORIGINAL [4096][1024]
    const float* __restrict__ h_in,  // [B, H]
    float* __restrict__ h_out,       // [B, H]
    float* __restrict__ c_cur,       // [B, H]
    float* __restrict__ h_seq,       // [T, B, H]
    int t) {
  __shared__ float hs[16 * 1024];  // 64 KB: 16 batches x 1024
  const int tid = threadIdx.x;
  const int j0 = blockIdx.x * 16;
  const int b0 = blockIdx.y * 16;
  // stage h_in rows b0..b0+15 (coalesced float4)
#pragma unroll
  for (int i = 0; i < 16; ++i) {
    int idx = i * 256 + tid;  // float4 index 0..4095
    int row = idx >> 8, c4 = idx & 255;
    ((float4*)hs)[row * 256 + c4] =
        *(const float4*)&h_in[(size_t)(b0 + row) * HH + c4 * 4];
  }
  __syncthreads();

  const int lane = tid & 63;
  const int w = tid >> 6;        // wave id -> batch quad
  const int g = lane >> 4;       // gate 0..3
  const int jl = lane & 15;      // j within tile
  const int c = g * HH + j0 + jl;  // gate-column 0..4095
  const int bq = 4 * w;            // local batch base
  const int tl = t & (TCHUNK - 1);

  const float4* w4 = (const float4*)(w_hh + (size_t)c * HH);  // 256 float4
  const float4* h0p = (const float4*)hs + (bq + 0) * 256;
  const float4* h1p = (const float4*)hs + (bq + 1) * 256;
  const float4* h2p = (const float4*)hs + (bq + 2) * 256;
  const float4* h3p = (const float4*)hs + (bq + 3) * 256;

  float a0 = xg[((size_t)(tl * BB + b0 + bq + 0)) * G4 + c];
  float a1 = xg[((size_t)(tl * BB + b0 + bq + 1)) * G4 + c];
  float a2 = xg[((size_t)(tl * BB + b0 + bq + 2)) * G4 + c];
  float a3 = xg[((size_t)(tl * BB + b0 + bq + 3)) * G4 + c];

#pragma unroll 8
  for (int k4 = 0; k4 < 256; ++k4) {
    float4 wv = w4[k4];
    float4 h0 = h0p[k4];
    float4 h1 = h1p[k4];
    float4 h2 = h2p[k4];
    float4 h3 = h3p[k4];
    a0 = fmaf(wv.x, h0.x, a0); a0 = fmaf(wv.y, h0.y, a0);
    a0 = fmaf(wv.z, h0.z, a0); a0 = fmaf(wv.w, h0.w, a0);
    a1 = fmaf(wv.x, h1.x, a1); a1 = fmaf(wv.y, h1.y, a1);
    a1 = fmaf(wv.z, h1.z, a1); a1 = fmaf(wv.w, h1.w, a1);
    a2 = fmaf(wv.x, h2.x, a2); a2 = fmaf(wv.y, h2.y, a2);
    a2 = fmaf(wv.z, h2.z, a2); a2 = fmaf(wv.w, h2.w, a2);
    a3 = fmaf(wv.x, h3.x, a3); a3 = fmaf(wv.y, h3.y, a3);
    a3 = fmaf(wv.z, h3.z, a3); a3 = fmaf(wv.w, h3.w, a3);
  }

  // exchange gates: lane L needs gate g' values for (j0+jl, b0+bq+gsel)
  const int gsel = g;  // reuse lane>>4 as batch-slot selector post-exchange
  float gate[4];
#pragma unroll
  for (int gg = 0; gg < 4; ++gg) {
    int src = gg * 16 + jl;
    float t0 = __shfl(a0, src, 64);
    float t1 = __shfl(a1, src, 64);
    float t2 = __shfl(a2, src, 64);
    float t3 = __shfl(a3, src, 64);
    gate[gg] = gsel == 0 ? t0 : gsel == 1 ? t1 : gsel == 2 ? t2 : t3;
  }
  const int b_out = b0 + bq + gsel;
  const int j = j0 + jl;
  size_t hidx = (size_t)b_out * HH + j;
  float cprev = c_cur[hidx];
  float ig = 1.f / (1.f + __expf(-gate[0]));
  float fg = 1.f / (1.f + __expf(-gate[1]));
  float gg2 = tanhf(gate[2]);
  float og = 1.f / (1.f + __expf(-gate[3]));
  float cn = fg * cprev + ig * gg2;
  float hn = og * tanhf(cn);
  c_cur[hidx] = cn;
  h_out[hidx] = hn;
  h_seq[((size_t)t * BB + b_out) * HH + j] = hn;
}

// ---------------- final FC ----------------
__global__ __launch_bounds__(256) void final_fc(
    const float* __restrict__ h_seq, const float* __restrict__ fc_w,
    const float* __restrict__ fc_b, float* __restrict__ out) {
  int b = blockIdx.x;
  const float* hrow = h_seq + ((size_t)(TT - 1) * BB + b) * HH;
  float s = 0.f;
  for (int j = threadIdx.x; j < HH; j += 256) s += hrow[j] * fc_w[j];
#pragma unroll
  for (int off = 32; off > 0; off >>= 1) s += __shfl_down(s, off, 64);
  __shared__ float wsum[4];
  int wv = threadIdx.x >> 6, ln = threadIdx.x & 63;
  if (ln == 0) wsum[wv] = s;
  __syncthreads();
  if (threadIdx.x == 0) out[b] = wsum[0] + wsum[1] + wsum[2] + wsum[3] + fc_b[0];
}

extern "C" void kernel_launch(void* const* d_in, const int* in_sizes, int n_in,
                              void* d_out, int out_size, void* d_ws,
                              size_t ws_size, hipStream_t stream) {
  const float* x = (const float*)d_in[0];
  const float* w_ih[3] = {(const float*)d_in[1], (const float*)d_in[5],
                          (const float*)d_in[9]};
  const float* w_hh[3] = {(const float*)d_in[2], (const float*)d_in[6],
                          (const float*)d_in[10]};
  const float* b_ih[3] = {(const float*)d_in[3], (const float*)d_in[7],
                          (const float*)d_in[11]};
  const float* b_hh[3] = {(const float*)d_in[4], (const float*)d_in[8],
                          (const float*)d_in[12]};
  const float* fc_w = (const float*)d_in[13];
  const float* fc_b = (const float*)d_in[14];
  float* out = (float*)d_out;

  char* ws = (char*)d_ws;
  size_t off = 0;
  auto alloc = [&](size_t bytes) {
    float* p = (float*)(ws + off);
    off += bytes;
    return p;
  };
  float* wt_ih[3];
  wt_ih[0] = alloc((size_t)DIN * G4 * 4);
  wt_ih[1] = alloc((size_t)HH * G4 * 4);
  wt_ih[2] = alloc((size_t)HH * G4 * 4);
  float* bias[3];
  for (int l = 0; l < 3; ++l) bias[l] = alloc((size_t)G4 * 4);
  float* h_a = alloc((size_t)BB * HH * 4);
  float* h_b = alloc((size_t)BB * HH * 4);
  float* c0 = alloc((size_t)BB * HH * 4);
  float* hseq = alloc((size_t)TT * BB * HH * 4);
  float* xg = alloc((size_t)TCHUNK * BB * G4 * 4);
  // ~165 MB

  transpose_f32<<<dim3(DIN / 32, G4 / 32), 256, 0, stream>>>(w_ih[0], wt_ih[0], G4, DIN);
  transpose_f32<<<dim3(HH / 32, G4 / 32), 256, 0, stream>>>(w_ih[1], wt_ih[1], G4, HH);
  transpose_f32<<<dim3(HH / 32, G4 / 32), 256, 0, stream>>>(w_ih[2], wt_ih[2], G4, HH);
  for (int l = 0; l < 3; ++l)
    bias_add<<<16, 256, 0, stream>>>(b_ih[l], b_hh[l], bias[l]);

  for (int l = 0; l < 3; ++l) {
    hipMemsetAsync(h_a, 0, (size_t)BB * HH * 4, stream);
    hipMemsetAsync(c0, 0, (size_t)BB * HH * 4, stream);
    int K = (l == 0) ? DIN : HH;
    const float* A = (l == 0) ? x : hseq;
    for (int c = 0; c < TT / TCHUNK; ++c) {
      proj_gemm2<<<dim3(G4 / 128, TCHUNK * BB / 128), 256, 0, stream>>>(
          A, wt_ih[l], bias[l], xg, K, (l == 0) ? 1 : 0, c * TCHUNK);
      for (int tt = 0; tt < TCHUNK; ++tt) {
        int t = c * TCHUNK + tt;
        float* hin = (t & 1) ? h_b : h_a;
        float* hout = (t & 1) ? h_a : h_b;
        lstm_step2<<<dim3(HH / 16, BB / 16), 256, 0, stream>>>(
            xg, w_hh[l], hin, hout, c0, hseq, t);
      }
    }
  }
  final_fc<<<BB, 256, 0, stream>>>(hseq, fc_w, fc_b, out);
}

// Round 3
// 11635.552 us; speedup vs baseline: 2.4345x; 2.4149x over previous
//
#include <hip/hip_runtime.h>

// LSTM_63402307223694 — Round 3: split-bf16 MFMA recurrence, packed operands.
// B=64, T=256, D_IN=256, H=1024, D_OUT=1, 3 layers, gates i,f,g,o.
//
// Recurrence GEMM per step: [64 x 1024] x [1024 x 4096] via 16x16x32 bf16
// MFMA, split-bf16 (hi+lo) x (hi+lo), 3 passes (hh, hl, lh) -> ~fp32 accuracy.
// Weights pre-packed per layer into per-lane B-frag order (coalesced b128,
// XCD-L2 resident). h packed into A-frag order by the fused pointwise of the
// previous step (double-buffered). No LDS / no barrier in the K-loop.
// proj_gemm2 (fp32 128x128) unchanged from R2.

#define BB 64
#define TT 256
#define DIN 256
#define HH 1024
#define G4 4096
#define TCHUNK 64

typedef __attribute__((ext_vector_type(8))) short short8;    // 8 bf16 = 4 VGPR
typedef __attribute__((ext_vector_type(4))) float floatx4;   // MFMA C/D

__device__ __forceinline__ unsigned short bf16_rne(float f) {
  union { float f; unsigned int u; } v; v.f = f;
  unsigned int lsb = (v.u >> 16) & 1u;
  v.u += 0x7fffu + lsb;
  return (unsigned short)(v.u >> 16);
}
__device__ __forceinline__ float bf16_to_f(unsigned short b) {
  union { float f; unsigned int u; } v; v.u = ((unsigned int)b) << 16;
  return v.f;
}

// ---------------- transpose (w_ih -> [K][4H] for proj) ----------------
__global__ __launch_bounds__(256) void transpose_f32(
    const float* __restrict__ src, float* __restrict__ dst, int R, int C) {
  __shared__ float tile[32][33];
  int c0 = blockIdx.x * 32, r0 = blockIdx.y * 32;
  int tx = threadIdx.x & 31, ty = threadIdx.x >> 5;
#pragma unroll
  for (int i = 0; i < 32; i += 8)
    tile[ty + i][tx] = src[(size_t)(r0 + ty + i) * C + (c0 + tx)];
  __syncthreads();
#pragma unroll
  for (int i = 0; i < 32; i += 8)
    dst[(size_t)(c0 + ty + i) * R + (r0 + tx)] = tile[tx][ty + i];
}

__global__ __launch_bounds__(256) void bias_add(
    const float* __restrict__ a, const float* __restrict__ b,
    float* __restrict__ o) {
  int i = blockIdx.x * 256 + threadIdx.x;
  o[i] = a[i] + b[i];
}

// ---------------- pack w_hh -> split-bf16 B-fragments ----------------
// Bhat[nsub 0..255][kk 0..31][lane 0..63][8 bf16], nsub = nt*2 + nw.
// lane: n = lane&15 -> (jj = n>>2, g = n&3), q = lane>>4.
// source row = g*1024 + nt*8 + nw*4 + jj ; k = kk*32 + q*8 + e.
__global__ __launch_bounds__(256) void pack_w(
    const float* __restrict__ w, unsigned short* __restrict__ bhi,
    unsigned short* __restrict__ blo) {
  int idx = blockIdx.x * 256 + threadIdx.x;  // slot, total 512K
  int lane = idx & 63;
  int kk = (idx >> 6) & 31;
  int nsub = idx >> 11;
  int n = lane & 15, q = lane >> 4;
  int jj = n >> 2, g = n & 3;
  int nt = nsub >> 1, nw = nsub & 1;
  int row = g * HH + nt * 8 + nw * 4 + jj;
  int kbase = kk * 32 + q * 8;
  const float* src = w + (size_t)row * HH + kbase;
  unsigned short h8[8], l8[8];
#pragma unroll
  for (int e = 0; e < 8; ++e) {
    float f = src[e];
    unsigned short hb = bf16_rne(f);
    h8[e] = hb;
    l8[e] = bf16_rne(f - bf16_to_f(hb));
  }
  *(short8*)(bhi + (size_t)idx * 8) = *(short8*)h8;
  *(short8*)(blo + (size_t)idx * 8) = *(short8*)l8;
}

// ---------------- projection GEMM (fp32 128x128, unchanged R2) ----------
__global__ __launch_bounds__(256) void proj_gemm2(
    const float* __restrict__ A, const float* __restrict__ Wt,
    const float* __restrict__ bias, float* __restrict__ xg,
    int K, int is_l0, int t_base) {
  __shared__ float As[16][132];
  __shared__ float Bs[16][132];
  const int n0 = blockIdx.x * 128;
  const int m0 = blockIdx.y * 128;
  const int tid = threadIdx.x;
  const int tn = tid & 15, tm = tid >> 4;
  float acc[8][8] = {};
  for (int k0 = 0; k0 < K; k0 += 16) {
#pragma unroll
    for (int i = 0; i < 2; ++i) {
      int fidx = i * 256 + tid;
      int m = fidx >> 2, kq = fidx & 3;
      int mrow = m0 + m;
      const float* arow;
      if (is_l0) {
        int mg = t_base * 64 + mrow;
        int b = mg & 63, t = mg >> 6;
        arow = A + (size_t)b * (DIN * TT) + (size_t)t * DIN;
      } else {
        arow = A + ((size_t)t_base * 64 + mrow) * HH;
      }
      float4 av = *(const float4*)&arow[k0 + kq * 4];
      As[kq * 4 + 0][m] = av.x;
      As[kq * 4 + 1][m] = av.y;
      As[kq * 4 + 2][m] = av.z;
      As[kq * 4 + 3][m] = av.w;
    }
#pragma unroll
    for (int i = 0; i < 2; ++i) {
      int fidx = i * 256 + tid;
      int kk = fidx >> 5, nq = fidx & 31;
      *(float4*)&Bs[kk][nq * 4] =
          *(const float4*)&Wt[(size_t)(k0 + kk) * G4 + n0 + nq * 4];
    }
    __syncthreads();
#pragma unroll
    for (int kk = 0; kk < 16; ++kk) {
      float4 a0 = *(const float4*)&As[kk][tm * 8];
      float4 a1 = *(const float4*)&As[kk][tm * 8 + 4];
      float4 b0 = *(const float4*)&Bs[kk][tn * 8];
      float4 b1 = *(const float4*)&Bs[kk][tn * 8 + 4];
      float av[8] = {a0.x, a0.y, a0.z, a0.w, a1.x, a1.y, a1.z, a1.w};
      float bv[8] = {b0.x, b0.y, b0.z, b0.w, b1.x, b1.y, b1.z, b1.w};
#pragma unroll
      for (int i = 0; i < 8; ++i)
#pragma unroll
        for (int j = 0; j < 8; ++j) acc[i][j] = fmaf(av[i], bv[j], acc[i][j]);
    }
    __syncthreads();
  }
  float4 bb0 = *(const float4*)&bias[n0 + tn * 8];
  float4 bb1 = *(const float4*)&bias[n0 + tn * 8 + 4];
  float bv[8] = {bb0.x, bb0.y, bb0.z, bb0.w, bb1.x, bb1.y, bb1.z, bb1.w};
#pragma unroll
  for (int r = 0; r < 8; ++r) {
    int m = m0 + tm * 8 + r;
    float4 o0, o1;
    o0.x = acc[r][0] + bv[0]; o0.y = acc[r][1] + bv[1];
    o0.z = acc[r][2] + bv[2]; o0.w = acc[r][3] + bv[3];
    o1.x = acc[r][4] + bv[4]; o1.y = acc[r][5] + bv[5];
    o1.z = acc[r][6] + bv[6]; o1.w = acc[r][7] + bv[7];
    *(float4*)&xg[(size_t)m * G4 + n0 + tn * 8] = o0;
    *(float4*)&xg[(size_t)m * G4 + n0 + tn * 8 + 4] = o1;
  }
}

// ---------------- MFMA LSTM step ----------------
// grid (128 n-tiles, 2 m-tiles), 256 thr = 4 waves = 2x2 subtiles of 16x16.
// Block: batches mp*32..+31, j = nt*8..+7 (x4 gates). K-loop: no LDS.
__global__ __launch_bounds__(256) void lstm_step_mfma(
    const unsigned short* __restrict__ Ahi,  // [4][32][64][8] packed h hi
    const unsigned short* __restrict__ Alo,
    const unsigned short* __restrict__ Bhi,  // [256][32][64][8] packed w
    const unsigned short* __restrict__ Blo,
    const float* __restrict__ xg,            // [64,B,4H] chunk
    float* __restrict__ c_cur,               // [B,H]
    float* __restrict__ hseq,                // [T,B,H]
    unsigned short* __restrict__ Nhi,        // next-step packed h
    unsigned short* __restrict__ Nlo,
    int t) {
  const int tid = threadIdx.x;
  const int lane = tid & 63;
  const int w = tid >> 6, mw = w & 1, nw = w >> 1;
  const int nt = blockIdx.x, mp = blockIdx.y;
  const int mt = mp * 2 + mw;
  const int nsub = nt * 2 + nw;

  const short8* pa_hi = (const short8*)(Ahi + ((size_t)mt * 2048 + lane * 8) * 8 / 8);
  const short8* pa_lo = (const short8*)(Alo + (size_t)mt * 16384 + lane * 8);
  const short8* pb_hi = (const short8*)(Bhi + (size_t)nsub * 16384 + lane * 8);
  const short8* pb_lo = (const short8*)(Blo + (size_t)nsub * 16384 + lane * 8);
  // fix pa_hi to the same formula (avoid the div trick above)
  pa_hi = (const short8*)(Ahi + (size_t)mt * 16384 + lane * 8);

  floatx4 acc = {0.f, 0.f, 0.f, 0.f};
#pragma unroll 4
  for (int kk = 0; kk < 32; ++kk) {
    short8 ahi = pa_hi[kk * 64];  // stride 64 short8 = 512 elems
    short8 alo = pa_lo[kk * 64];
    short8 bhi = pb_hi[kk * 64];
    short8 blo = pb_lo[kk * 64];
    acc = __builtin_amdgcn_mfma_f32_16x16x32_bf16(ahi, bhi, acc, 0, 0, 0);
    acc = __builtin_amdgcn_mfma_f32_16x16x32_bf16(ahi, blo, acc, 0, 0, 0);
    acc = __builtin_amdgcn_mfma_f32_16x16x32_bf16(alo, bhi, acc, 0, 0, 0);
  }

  // C/D layout: col = lane&15, row = (lane>>4)*4 + reg  [m89-verified]
  __shared__ float gbuf[32 * 36];  // [b_local][n_local], pad 36
  {
    int col = lane & 15, rowq = lane >> 4;
#pragma unroll
    for (int r = 0; r < 4; ++r) {
      int bl = mw * 16 + rowq * 4 + r;
      int nl = nw * 16 + col;
      gbuf[bl * 36 + nl] = acc[r];
    }
  }
  __syncthreads();

  // pointwise: thread = (b_local = tid>>3, j_local = tid&7)
  {
    int bl = tid >> 3, jl = tid & 7;
    int nlbase = (jl >> 2) * 16 + (jl & 3) * 4;  // n_local of gate 0
    float4 gv = *(float4*)&gbuf[bl * 36 + nlbase];  // i,f,g,o
    int b = mp * 32 + bl;
    int j = nt * 8 + jl;
    int tl = t & (TCHUNK - 1);
    const float* xgp = xg + ((size_t)(tl * BB + b)) * G4 + j;
    float gi = gv.x + xgp[0];
    float gf = gv.y + xgp[HH];
    float gg = gv.z + xgp[2 * HH];
    float go = gv.w + xgp[3 * HH];
    size_t hidx = (size_t)b * HH + j;
    float cprev = c_cur[hidx];
    float ig = 1.f / (1.f + __expf(-gi));
    float fg = 1.f / (1.f + __expf(-gf));
    float g2 = tanhf(gg);
    float og = 1.f / (1.f + __expf(-go));
    float cn = fg * cprev + ig * g2;
    float hn = og * tanhf(cn);
    c_cur[hidx] = cn;
    hseq[((size_t)t * BB + b) * HH + j] = hn;
    // pack hn into next-step A-frag layout
    unsigned short hb = bf16_rne(hn);
    unsigned short lb = bf16_rne(hn - bf16_to_f(hb));
    int mt2 = b >> 4, m2 = b & 15, kk2 = j >> 5, q2 = (j >> 3) & 3, e2 = j & 7;
    size_t slot = (((size_t)mt2 * 32 + kk2) * 64 + q2 * 16 + m2) * 8 + e2;
    Nhi[slot] = hb;
    Nlo[slot] = lb;
  }
}

// ---------------- final FC ----------------
__global__ __launch_bounds__(256) void final_fc(
    const float* __restrict__ h_seq, const float* __restrict__ fc_w,
    const float* __restrict__ fc_b, float* __restrict__ out) {
  int b = blockIdx.x;
  const float* hrow = h_seq + ((size_t)(TT - 1) * BB + b) * HH;
  float s = 0.f;
  for (int j = threadIdx.x; j < HH; j += 256) s += hrow[j] * fc_w[j];
#pragma unroll
  for (int off = 32; off > 0; off >>= 1) s += __shfl_down(s, off, 64);
  __shared__ float wsum[4];
  int wv = threadIdx.x >> 6, ln = threadIdx.x & 63;
  if (ln == 0) wsum[wv] = s;
  __syncthreads();
  if (threadIdx.x == 0) out[b] = wsum[0] + wsum[1] + wsum[2] + wsum[3] + fc_b[0];
}

extern "C" void kernel_launch(void* const* d_in, const int* in_sizes, int n_in,
                              void* d_out, int out_size, void* d_ws,
                              size_t ws_size, hipStream_t stream) {
  const float* x = (const float*)d_in[0];
  const float* w_ih[3] = {(const float*)d_in[1], (const float*)d_in[5],
                          (const float*)d_in[9]};
  const float* w_hh[3] = {(const float*)d_in[2], (const float*)d_in[6],
                          (const float*)d_in[10]};
  const float* b_ih[3] = {(const float*)d_in[3], (const float*)d_in[7],
                          (const float*)d_in[11]};
  const float* b_hh[3] = {(const float*)d_in[4], (const float*)d_in[8],
                          (const float*)d_in[12]};
  const float* fc_w = (const float*)d_in[13];
  const float* fc_b = (const float*)d_in[14];
  float* out = (float*)d_out;

  char* ws = (char*)d_ws;
  size_t off = 0;
  auto alloc = [&](size_t bytes) {
    void* p = (void*)(ws + off);
    off += (bytes + 255) & ~(size_t)255;
    return p;
  };
  float* wt_ih[3];
  wt_ih[0] = (float*)alloc((size_t)DIN * G4 * 4);
  wt_ih[1] = (float*)alloc((size_t)HH * G4 * 4);
  wt_ih[2] = (float*)alloc((size_t)HH * G4 * 4);
  float* bias[3];
  for (int l = 0; l < 3; ++l) bias[l] = (float*)alloc((size_t)G4 * 4);
  unsigned short* Bhi[3];
  unsigned short* Blo[3];
  for (int l = 0; l < 3; ++l) {
    Bhi[l] = (unsigned short*)alloc((size_t)G4 * HH * 2);
    Blo[l] = (unsigned short*)alloc((size_t)G4 * HH * 2);
  }
  unsigned short* Aa_hi = (unsigned short*)alloc((size_t)BB * HH * 2);
  unsigned short* Aa_lo = (unsigned short*)alloc((size_t)BB * HH * 2);
  unsigned short* Ab_hi = (unsigned short*)alloc((size_t)BB * HH * 2);
  unsigned short* Ab_lo = (unsigned short*)alloc((size_t)BB * HH * 2);
  float* c0 = (float*)alloc((size_t)BB * HH * 4);
  float* hseq = (float*)alloc((size_t)TT * BB * HH * 4);
  float* xg = (float*)alloc((size_t)TCHUNK * BB * G4 * 4);
  // ~215 MB

  transpose_f32<<<dim3(DIN / 32, G4 / 32), 256, 0, stream>>>(w_ih[0], wt_ih[0], G4, DIN);
  transpose_f32<<<dim3(HH / 32, G4 / 32), 256, 0, stream>>>(w_ih[1], wt_ih[1], G4, HH);
  transpose_f32<<<dim3(HH / 32, G4 / 32), 256, 0, stream>>>(w_ih[2], wt_ih[2], G4, HH);
  for (int l = 0; l < 3; ++l)
    bias_add<<<16, 256, 0, stream>>>(b_ih[l], b_hh[l], bias[l]);
  for (int l = 0; l < 3; ++l)
    pack_w<<<2048, 256, 0, stream>>>(w_hh[l], Bhi[l], Blo[l]);

  for (int l = 0; l < 3; ++l) {
    hipMemsetAsync(Aa_hi, 0, (size_t)BB * HH * 2, stream);
    hipMemsetAsync(Aa_lo, 0, (size_t)BB * HH * 2, stream);
    hipMemsetAsync(c0, 0, (size_t)BB * HH * 4, stream);
    int K = (l == 0) ? DIN : HH;
    const float* A = (l == 0) ? x : hseq;
    for (int c = 0; c < TT / TCHUNK; ++c) {
      proj_gemm2<<<dim3(G4 / 128, TCHUNK * BB / 128), 256, 0, stream>>>(
          A, wt_ih[l], bias[l], xg, K, (l == 0) ? 1 : 0, c * TCHUNK);
      for (int tt = 0; tt < TCHUNK; ++tt) {
        int t = c * TCHUNK + tt;
        unsigned short *cah, *cal, *nah, *nal;
        if (t & 1) { cah = Ab_hi; cal = Ab_lo; nah = Aa_hi; nal = Aa_lo; }
        else       { cah = Aa_hi; cal = Aa_lo; nah = Ab_hi; nal = Ab_lo; }
        lstm_step_mfma<<<dim3(128, 2), 256, 0, stream>>>(
            cah, cal, Bhi[l], Blo[l], xg, c0, hseq, nah, nal, t);
      }
    }
  }
  final_fc<<<BB, 256, 0, stream>>>(hseq, fc_w, fc_b, out);
}

// Round 4
// 8107.910 us; speedup vs baseline: 3.4937x; 1.4351x over previous
//
#include <hip/hip_runtime.h>

// LSTM_63402307223694 — Round 4: MFMA everywhere (split-bf16), K-split steps.
// B=64, T=256, D_IN=256, H=1024, D_OUT=1, 3 layers, gates i,f,g,o.
//
// - proj_mfma: xg = A @ w_ih^T + bias via packed split-bf16 fragments.
//   A-fragments (PA) written by the previous layer's step epilogue (or pack_x
//   for layer 0); B-fragments (PB) packed once per layer.
// - lstm_step_mfma2: 512 thr, 8 waves = 2x2 tile subgrid x 2-way K-split
//   (2 waves/SIMD). Partial C summed via LDS, fused pointwise + repack
//   (next-step recurrence A-frags AND next-layer proj A-frags).
// - No fp32 hseq: only hlast [B,H] kept for the final FC.

#define BB 64
#define TT 256
#define DIN 256
#define HH 1024
#define G4 4096
#define TCHUNK 64

typedef __attribute__((ext_vector_type(8))) short short8;
typedef __attribute__((ext_vector_type(4))) float floatx4;

__device__ __forceinline__ unsigned short bf16_rne(float f) {
  union { float f; unsigned int u; } v; v.f = f;
  unsigned int lsb = (v.u >> 16) & 1u;
  v.u += 0x7fffu + lsb;
  return (unsigned short)(v.u >> 16);
}
__device__ __forceinline__ float bf16_to_f(unsigned short b) {
  union { float f; unsigned int u; } v; v.u = ((unsigned int)b) << 16;
  return v.f;
}

__global__ __launch_bounds__(256) void bias_add(
    const float* __restrict__ a, const float* __restrict__ b,
    float* __restrict__ o) {
  int i = blockIdx.x * 256 + threadIdx.x;
  o[i] = a[i] + b[i];
}

// ---- pack w_hh -> recurrence B-frags (gate-interleaved n), NKK=32 ----
// slot idx = ((nsub*32 + kk)*64 + lane); lane: n=lane&15 -> jj=n>>2,g=n&3.
__global__ __launch_bounds__(256) void pack_w(
    const float* __restrict__ w, unsigned short* __restrict__ bhi,
    unsigned short* __restrict__ blo) {
  int idx = blockIdx.x * 256 + threadIdx.x;  // 524288 total
  int lane = idx & 63;
  int kk = (idx >> 6) & 31;
  int nsub = idx >> 11;
  int n = lane & 15, q = lane >> 4;
  int jj = n >> 2, g = n & 3;
  int nt = nsub >> 1, nw = nsub & 1;
  int row = g * HH + nt * 8 + nw * 4 + jj;
  int kbase = kk * 32 + q * 8;
  const float* src = w + (size_t)row * HH + kbase;
  unsigned short h8[8], l8[8];
#pragma unroll
  for (int e = 0; e < 8; ++e) {
    float f = src[e];
    unsigned short hb = bf16_rne(f);
    h8[e] = hb;
    l8[e] = bf16_rne(f - bf16_to_f(hb));
  }
  *(short8*)(bhi + (size_t)idx * 8) = *(short8*)h8;
  *(short8*)(blo + (size_t)idx * 8) = *(short8*)l8;
}

// ---- pack w_ih -> proj B-frags (direct n = gate-major row), K = 256/1024 --
__global__ __launch_bounds__(256) void pack_wih(
    const float* __restrict__ w, unsigned short* __restrict__ bh,
    unsigned short* __restrict__ bl, int K, int lgNKK) {
  int idx = blockIdx.x * 256 + threadIdx.x;  // nsub*NKK*64 total
  int lane = idx & 63;
  int rest = idx >> 6;
  int kk = rest & ((1 << lgNKK) - 1);
  int nsub = rest >> lgNKK;
  int n = nsub * 16 + (lane & 15);
  int kbase = kk * 32 + (lane >> 4) * 8;
  const float* src = w + (size_t)n * K + kbase;
  unsigned short h8[8], l8[8];
#pragma unroll
  for (int e = 0; e < 8; ++e) {
    float f = src[e];
    unsigned short hb = bf16_rne(f);
    h8[e] = hb;
    l8[e] = bf16_rne(f - bf16_to_f(hb));
  }
  *(short8*)(bh + (size_t)idx * 8) = *(short8*)h8;
  *(short8*)(bl + (size_t)idx * 8) = *(short8*)l8;
}

// ---- pack x -> layer-0 proj A-frags. Row R = t*64+b, K=256 (NKK=8) ----
__global__ __launch_bounds__(256) void pack_x(
    const float* __restrict__ x, unsigned short* __restrict__ ph,
    unsigned short* __restrict__ pl) {
  int idx = blockIdx.x * 256 + threadIdx.x;  // 1024 mt * 8 kk * 64 = 524288
  int lane = idx & 63;
  int kk = (idx >> 6) & 7;
  int mt = idx >> 9;
  int m2 = lane & 15, q = lane >> 4;
  int R = mt * 16 + m2;
  int t = R >> 6, b = R & 63;
  int k = kk * 32 + q * 8;
  const float* src = x + (size_t)b * (DIN * TT) + (size_t)t * DIN + k;
  unsigned short h8[8], l8[8];
#pragma unroll
  for (int e = 0; e < 8; ++e) {
    float f = src[e];
    unsigned short hb = bf16_rne(f);
    h8[e] = hb;
    l8[e] = bf16_rne(f - bf16_to_f(hb));
  }
  *(short8*)(ph + (size_t)idx * 8) = *(short8*)h8;
  *(short8*)(pl + (size_t)idx * 8) = *(short8*)l8;
}

// ---- projection GEMM via MFMA split-bf16 ----
// Chunk: M=4096 rows (tl*64+b), N=4096, K = NKK*32.
// Grid (32,32); block 256 thr = 4 waves (2x2), wave = 4x4 16x16 tiles.
__global__ __launch_bounds__(256) void proj_mfma(
    const unsigned short* __restrict__ PAh,
    const unsigned short* __restrict__ PAl,
    const unsigned short* __restrict__ PBh,
    const unsigned short* __restrict__ PBl,
    const float* __restrict__ bias, float* __restrict__ xg, int NKK) {
  const int tid = threadIdx.x, lane = tid & 63, w = tid >> 6;
  const int mw = w & 1, nw = w >> 1;
  const int mtB = blockIdx.y * 8 + mw * 4;
  const int nsB = blockIdx.x * 8 + nw * 4;
  const short8* A8h = (const short8*)PAh;
  const short8* A8l = (const short8*)PAl;
  const short8* B8h = (const short8*)PBh;
  const short8* B8l = (const short8*)PBl;
  floatx4 acc[4][4] = {};
  for (int kk = 0; kk < NKK; ++kk) {
    short8 ah[4], al[4], bh[4], bl[4];
#pragma unroll
    for (int i = 0; i < 4; ++i) {
      size_t s = ((size_t)(mtB + i) * NKK + kk) * 64 + lane;
      ah[i] = A8h[s];
      al[i] = A8l[s];
    }
#pragma unroll
    for (int j = 0; j < 4; ++j) {
      size_t s = ((size_t)(nsB + j) * NKK + kk) * 64 + lane;
      bh[j] = B8h[s];
      bl[j] = B8l[s];
    }
#pragma unroll
    for (int i = 0; i < 4; ++i)
#pragma unroll
      for (int j = 0; j < 4; ++j) {
        acc[i][j] = __builtin_amdgcn_mfma_f32_16x16x32_bf16(ah[i], bh[j], acc[i][j], 0, 0, 0);
        acc[i][j] = __builtin_amdgcn_mfma_f32_16x16x32_bf16(ah[i], bl[j], acc[i][j], 0, 0, 0);
        acc[i][j] = __builtin_amdgcn_mfma_f32_16x16x32_bf16(al[i], bh[j], acc[i][j], 0, 0, 0);
      }
  }
  // C/D: col=lane&15 (n), row=(lane>>4)*4+reg (m)
  const int col = lane & 15, rowq = lane >> 4;
#pragma unroll
  for (int j = 0; j < 4; ++j) {
    int n = (nsB + j) * 16 + col;
    float bz = bias[n];
#pragma unroll
    for (int i = 0; i < 4; ++i) {
      int mbase = (mtB + i) * 16 + rowq * 4;
#pragma unroll
      for (int r = 0; r < 4; ++r)
        xg[(size_t)(mbase + r) * G4 + n] = acc[i][j][r] + bz;
    }
  }
}

// ---- LSTM step: 512 thr, 8 waves, 2-way K-split ----
// grid (128 nt, 2 mp). wave: mw=w&1, nw=(w>>1)&1, ks=w>>2.
__global__ __launch_bounds__(512) void lstm_step_mfma2(
    const unsigned short* __restrict__ Ahi,  // [4 mt][32 kk][64][8]
    const unsigned short* __restrict__ Alo,
    const unsigned short* __restrict__ Bhi,  // [256 nsub][32 kk][64][8]
    const unsigned short* __restrict__ Blo,
    const float* __restrict__ xg,   // chunk [64, B, 4H]
    float* __restrict__ c_cur,      // [B, H]
    float* __restrict__ hlast,      // [B, H]
    unsigned short* __restrict__ Nhi,  // next-step recurrence A-frags
    unsigned short* __restrict__ Nlo,
    unsigned short* __restrict__ PAh,  // next-layer proj A-frags (full T)
    unsigned short* __restrict__ PAl,
    int t) {
  __shared__ float gbuf[2][32][40];
  const int tid = threadIdx.x, lane = tid & 63, w = tid >> 6;
  const int mw = w & 1, nw = (w >> 1) & 1, ks = w >> 2;
  const int nt = blockIdx.x, mp = blockIdx.y;
  const int mt = mp * 2 + mw, nsub = nt * 2 + nw;
  const short8* pa_hi = (const short8*)Ahi + (size_t)mt * 2048 + lane;
  const short8* pa_lo = (const short8*)Alo + (size_t)mt * 2048 + lane;
  const short8* pb_hi = (const short8*)Bhi + (size_t)nsub * 2048 + lane;
  const short8* pb_lo = (const short8*)Blo + (size_t)nsub * 2048 + lane;

  floatx4 acc = {0.f, 0.f, 0.f, 0.f};
  const int k0 = ks * 16;
#pragma unroll 4
  for (int kk = k0; kk < k0 + 16; ++kk) {
    short8 ahi = pa_hi[(size_t)kk * 64];
    short8 alo = pa_lo[(size_t)kk * 64];
    short8 bhi = pb_hi[(size_t)kk * 64];
    short8 blo = pb_lo[(size_t)kk * 64];
    acc = __builtin_amdgcn_mfma_f32_16x16x32_bf16(ahi, bhi, acc, 0, 0, 0);
    acc = __builtin_amdgcn_mfma_f32_16x16x32_bf16(ahi, blo, acc, 0, 0, 0);
    acc = __builtin_amdgcn_mfma_f32_16x16x32_bf16(alo, bhi, acc, 0, 0, 0);
  }
  {
    int col = lane & 15, rowq = lane >> 4;
#pragma unroll
    for (int r = 0; r < 4; ++r)
      gbuf[ks][mw * 16 + rowq * 4 + r][nw * 16 + col] = acc[r];
  }
  __syncthreads();
  if (tid < 256) {
    int bl = tid >> 3, jl = tid & 7;
    int nlbase = (jl >> 2) * 16 + (jl & 3) * 4;
    float4 ga = *(float4*)&gbuf[0][bl][nlbase];
    float4 gb = *(float4*)&gbuf[1][bl][nlbase];
    int b = mp * 32 + bl;
    int j = nt * 8 + jl;
    int tl = t & (TCHUNK - 1);
    const float* xgp = xg + (size_t)(tl * BB + b) * G4 + j;
    float gi = ga.x + gb.x + xgp[0];
    float gf = ga.y + gb.y + xgp[HH];
    float gg = ga.z + gb.z + xgp[2 * HH];
    float go = ga.w + gb.w + xgp[3 * HH];
    size_t hidx = (size_t)b * HH + j;
    float cprev = c_cur[hidx];
    float ig = 1.f / (1.f + __expf(-gi));
    float fg = 1.f / (1.f + __expf(-gf));
    float g2 = tanhf(gg);
    float og = 1.f / (1.f + __expf(-go));
    float cn = fg * cprev + ig * g2;
    float hn = og * tanhf(cn);
    c_cur[hidx] = cn;
    hlast[hidx] = hn;
    unsigned short hb = bf16_rne(hn);
    unsigned short lb = bf16_rne(hn - bf16_to_f(hb));
    // recurrence A-frag (rows = b)
    size_t slotN = (((size_t)(b >> 4) * 32 + (j >> 5)) * 64 +
                    ((j >> 3) & 3) * 16 + (b & 15)) * 8 + (j & 7);
    Nhi[slotN] = hb;
    Nlo[slotN] = lb;
    // proj A-frag for next layer (rows R = t*64+b)
    int R = t * 64 + b;
    size_t slotP = (((size_t)(R >> 4) * 32 + (j >> 5)) * 64 +
                    ((j >> 3) & 3) * 16 + (b & 15)) * 8 + (j & 7);
    PAh[slotP] = hb;
    PAl[slotP] = lb;
  }
}

// ---- final FC: out[b] = hlast[b,:] . fc_w + fc_b ----
__global__ __launch_bounds__(256) void final_fc(
    const float* __restrict__ hlast, const float* __restrict__ fc_w,
    const float* __restrict__ fc_b, float* __restrict__ out) {
  int b = blockIdx.x;
  const float* hrow = hlast + (size_t)b * HH;
  float s = 0.f;
  for (int j = threadIdx.x; j < HH; j += 256) s += hrow[j] * fc_w[j];
#pragma unroll
  for (int off = 32; off > 0; off >>= 1) s += __shfl_down(s, off, 64);
  __shared__ float wsum[4];
  int wv = threadIdx.x >> 6, ln = threadIdx.x & 63;
  if (ln == 0) wsum[wv] = s;
  __syncthreads();
  if (threadIdx.x == 0) out[b] = wsum[0] + wsum[1] + wsum[2] + wsum[3] + fc_b[0];
}

extern "C" void kernel_launch(void* const* d_in, const int* in_sizes, int n_in,
                              void* d_out, int out_size, void* d_ws,
                              size_t ws_size, hipStream_t stream) {
  const float* x = (const float*)d_in[0];
  const float* w_ih[3] = {(const float*)d_in[1], (const float*)d_in[5],
                          (const float*)d_in[9]};
  const float* w_hh[3] = {(const float*)d_in[2], (const float*)d_in[6],
                          (const float*)d_in[10]};
  const float* b_ih[3] = {(const float*)d_in[3], (const float*)d_in[7],
                          (const float*)d_in[11]};
  const float* b_hh[3] = {(const float*)d_in[4], (const float*)d_in[8],
                          (const float*)d_in[12]};
  const float* fc_w = (const float*)d_in[13];
  const float* fc_b = (const float*)d_in[14];
  float* out = (float*)d_out;

  char* ws = (char*)d_ws;
  size_t off = 0;
  auto alloc = [&](size_t bytes) {
    void* p = (void*)(ws + off);
    off += (bytes + 255) & ~(size_t)255;
    return p;
  };
  // recurrence weights (B-frags)
  unsigned short *Bhi[3], *Blo[3];
  for (int l = 0; l < 3; ++l) {
    Bhi[l] = (unsigned short*)alloc((size_t)G4 * HH * 2);
    Blo[l] = (unsigned short*)alloc((size_t)G4 * HH * 2);
  }
  // proj weights (B-frags): l0 K=256, else K=1024
  unsigned short *PBh[3], *PBl[3];
  for (int l = 0; l < 3; ++l) {
    size_t K = (l == 0) ? DIN : HH;
    PBh[l] = (unsigned short*)alloc((size_t)G4 * K * 2);
    PBl[l] = (unsigned short*)alloc((size_t)G4 * K * 2);
  }
  float* bias[3];
  for (int l = 0; l < 3; ++l) bias[l] = (float*)alloc((size_t)G4 * 4);
  // proj A-frags: x (K=256) and inter-layer h (K=1024), full T
  unsigned short* PAxh = (unsigned short*)alloc((size_t)TT * BB * DIN * 2);
  unsigned short* PAxl = (unsigned short*)alloc((size_t)TT * BB * DIN * 2);
  unsigned short* PAh = (unsigned short*)alloc((size_t)TT * BB * HH * 2);
  unsigned short* PAl = (unsigned short*)alloc((size_t)TT * BB * HH * 2);
  // recurrence A-frags, double-buffered
  unsigned short* Aa_hi = (unsigned short*)alloc((size_t)BB * HH * 2);
  unsigned short* Aa_lo = (unsigned short*)alloc((size_t)BB * HH * 2);
  unsigned short* Ab_hi = (unsigned short*)alloc((size_t)BB * HH * 2);
  unsigned short* Ab_lo = (unsigned short*)alloc((size_t)BB * HH * 2);
  float* c0 = (float*)alloc((size_t)BB * HH * 4);
  float* hlast = (float*)alloc((size_t)BB * HH * 4);
  float* xg = (float*)alloc((size_t)TCHUNK * BB * G4 * 4);
  // total ~230 MB

  for (int l = 0; l < 3; ++l) {
    pack_w<<<2048, 256, 0, stream>>>(w_hh[l], Bhi[l], Blo[l]);
    int K = (l == 0) ? DIN : HH;
    int lg = (l == 0) ? 3 : 5;
    int slots = 256 * (K >> 5) * 64;
    pack_wih<<<slots / 256, 256, 0, stream>>>(w_ih[l], PBh[l], PBl[l], K, lg);
    bias_add<<<16, 256, 0, stream>>>(b_ih[l], b_hh[l], bias[l]);
  }
  pack_x<<<2048, 256, 0, stream>>>(x, PAxh, PAxl);

  for (int l = 0; l < 3; ++l) {
    hipMemsetAsync(Aa_hi, 0, (size_t)BB * HH * 2, stream);
    hipMemsetAsync(Aa_lo, 0, (size_t)BB * HH * 2, stream);
    hipMemsetAsync(c0, 0, (size_t)BB * HH * 4, stream);
    int NKK = (l == 0) ? (DIN / 32) : (HH / 32);
    for (int c = 0; c < TT / TCHUNK; ++c) {
      size_t aoff = (size_t)c * 256 * NKK * 512;  // 256 mt/chunk
      const unsigned short* pah = ((l == 0) ? PAxh : PAh) + aoff;
      const unsigned short* pal = ((l == 0) ? PAxl : PAl) + aoff;
      proj_mfma<<<dim3(32, 32), 256, 0, stream>>>(
          pah, pal, PBh[l], PBl[l], bias[l], xg, NKK);
      for (int tt = 0; tt < TCHUNK; ++tt) {
        int t = c * TCHUNK + tt;
        unsigned short *cah, *cal, *nah, *nal;
        if (t & 1) { cah = Ab_hi; cal = Ab_lo; nah = Aa_hi; nal = Aa_lo; }
        else       { cah = Aa_hi; cal = Aa_lo; nah = Ab_hi; nal = Ab_lo; }
        lstm_step_mfma2<<<dim3(128, 2), 512, 0, stream>>>(
            cah, cal, Bhi[l], Blo[l], xg, c0, hlast, nah, nal, PAh, PAl, t);
      }
    }
  }
  final_fc<<<BB, 256, 0, stream>>>(hlast, fc_w, fc_b, out);
}

// Round 5
// 7198.986 us; speedup vs baseline: 3.9348x; 1.1263x over previous
//
#include <hip/hip_runtime.h>

// LSTM_63402307223694 — Round 5: diagonal layer pipeline.
// B=64, T=256, D_IN=256, H=1024, D_OUT=1, 3 layers, gates i,f,g,o.
//
// Dispatch d computes (l=0,t=d), (l=1,t=d-1), (l=2,t=d-2) concurrently
// (blockIdx.z = layer). 258 step dispatches instead of 768.
// For l>0 the input projection Wih@h_{l-1}(t) is fused into the step as a
// second split-bf16 GEMM into the same accumulator (no xg for l>0).
// Layer 0 reads precomputed xg (4 chunked proj_mfma dispatches, K=256).
// h stored per-layer, parity-double-buffered, in MFMA A-frag layout
// (written by the step epilogue; serves both the recurrence of layer l and
// the input GEMM of layer l+1).

#define BB 64
#define TT 256
#define DIN 256
#define HH 1024
#define G4 4096
#define TCHUNK 64
#define HFRAG (BB * HH)  // shorts per frag buffer (128 KB)

typedef __attribute__((ext_vector_type(8))) short short8;
typedef __attribute__((ext_vector_type(4))) float floatx4;

__device__ __forceinline__ unsigned short bf16_rne(float f) {
  union { float f; unsigned int u; } v; v.f = f;
  unsigned int lsb = (v.u >> 16) & 1u;
  v.u += 0x7fffu + lsb;
  return (unsigned short)(v.u >> 16);
}
__device__ __forceinline__ float bf16_to_f(unsigned short b) {
  union { float f; unsigned int u; } v; v.u = ((unsigned int)b) << 16;
  return v.f;
}

__global__ __launch_bounds__(256) void bias_add(
    const float* __restrict__ a, const float* __restrict__ b,
    float* __restrict__ o) {
  int i = blockIdx.x * 256 + threadIdx.x;
  o[i] = a[i] + b[i];
}

// ---- pack a [4096 x 1024] weight -> gate-interleaved B-frags (NKK=32) ----
// slot idx = ((nsub*32 + kk)*64 + lane); lane: n=lane&15 -> jj=n>>2, g=n&3.
// Used for w_hh[0..2] AND w_ih[1..2] (same shape).
__global__ __launch_bounds__(256) void pack_w(
    const float* __restrict__ w, unsigned short* __restrict__ bhi,
    unsigned short* __restrict__ blo) {
  int idx = blockIdx.x * 256 + threadIdx.x;  // 524288 total
  int lane = idx & 63;
  int kk = (idx >> 6) & 31;
  int nsub = idx >> 11;
  int n = lane & 15, q = lane >> 4;
  int jj = n >> 2, g = n & 3;
  int nt = nsub >> 1, nw = nsub & 1;
  int row = g * HH + nt * 8 + nw * 4 + jj;
  int kbase = kk * 32 + q * 8;
  const float* src = w + (size_t)row * HH + kbase;
  unsigned short h8[8], l8[8];
#pragma unroll
  for (int e = 0; e < 8; ++e) {
    float f = src[e];
    unsigned short hb = bf16_rne(f);
    h8[e] = hb;
    l8[e] = bf16_rne(f - bf16_to_f(hb));
  }
  *(short8*)(bhi + (size_t)idx * 8) = *(short8*)h8;
  *(short8*)(blo + (size_t)idx * 8) = *(short8*)l8;
}

// ---- pack w_ih[0] -> proj B-frags (direct n rows), K=256 (NKK=8) ----
__global__ __launch_bounds__(256) void pack_wih0(
    const float* __restrict__ w, unsigned short* __restrict__ bh,
    unsigned short* __restrict__ bl) {
  int idx = blockIdx.x * 256 + threadIdx.x;  // 256 nsub * 8 kk * 64 = 131072
  int lane = idx & 63;
  int kk = (idx >> 6) & 7;
  int nsub = idx >> 9;
  int n = nsub * 16 + (lane & 15);
  int kbase = kk * 32 + (lane >> 4) * 8;
  const float* src = w + (size_t)n * DIN + kbase;
  unsigned short h8[8], l8[8];
#pragma unroll
  for (int e = 0; e < 8; ++e) {
    float f = src[e];
    unsigned short hb = bf16_rne(f);
    h8[e] = hb;
    l8[e] = bf16_rne(f - bf16_to_f(hb));
  }
  *(short8*)(bh + (size_t)idx * 8) = *(short8*)h8;
  *(short8*)(bl + (size_t)idx * 8) = *(short8*)l8;
}

// ---- pack x -> layer-0 proj A-frags. Row R = t*64+b, K=256 (NKK=8) ----
__global__ __launch_bounds__(256) void pack_x(
    const float* __restrict__ x, unsigned short* __restrict__ ph,
    unsigned short* __restrict__ pl) {
  int idx = blockIdx.x * 256 + threadIdx.x;  // 1024 mt * 8 kk * 64 = 524288
  int lane = idx & 63;
  int kk = (idx >> 6) & 7;
  int mt = idx >> 9;
  int m2 = lane & 15, q = lane >> 4;
  int R = mt * 16 + m2;
  int t = R >> 6, b = R & 63;
  int k = kk * 32 + q * 8;
  const float* src = x + (size_t)b * (DIN * TT) + (size_t)t * DIN + k;
  unsigned short h8[8], l8[8];
#pragma unroll
  for (int e = 0; e < 8; ++e) {
    float f = src[e];
    unsigned short hb = bf16_rne(f);
    h8[e] = hb;
    l8[e] = bf16_rne(f - bf16_to_f(hb));
  }
  *(short8*)(ph + (size_t)idx * 8) = *(short8*)h8;
  *(short8*)(pl + (size_t)idx * 8) = *(short8*)l8;
}

// ---- layer-0 projection GEMM (chunk of 64 t): M=4096, N=4096, K=256 ----
__global__ __launch_bounds__(256) void proj_mfma(
    const unsigned short* __restrict__ PAh,
    const unsigned short* __restrict__ PAl,
    const unsigned short* __restrict__ PBh,
    const unsigned short* __restrict__ PBl,
    const float* __restrict__ bias, float* __restrict__ xg, int NKK) {
  const int tid = threadIdx.x, lane = tid & 63, w = tid >> 6;
  const int mw = w & 1, nw = w >> 1;
  const int mtB = blockIdx.y * 8 + mw * 4;
  const int nsB = blockIdx.x * 8 + nw * 4;
  const short8* A8h = (const short8*)PAh;
  const short8* A8l = (const short8*)PAl;
  const short8* B8h = (const short8*)PBh;
  const short8* B8l = (const short8*)PBl;
  floatx4 acc[4][4] = {};
  for (int kk = 0; kk < NKK; ++kk) {
    short8 ah[4], al[4], bh[4], bl[4];
#pragma unroll
    for (int i = 0; i < 4; ++i) {
      size_t s = ((size_t)(mtB + i) * NKK + kk) * 64 + lane;
      ah[i] = A8h[s];
      al[i] = A8l[s];
    }
#pragma unroll
    for (int j = 0; j < 4; ++j) {
      size_t s = ((size_t)(nsB + j) * NKK + kk) * 64 + lane;
      bh[j] = B8h[s];
      bl[j] = B8l[s];
    }
#pragma unroll
    for (int i = 0; i < 4; ++i)
#pragma unroll
      for (int j = 0; j < 4; ++j) {
        acc[i][j] = __builtin_amdgcn_mfma_f32_16x16x32_bf16(ah[i], bh[j], acc[i][j], 0, 0, 0);
        acc[i][j] = __builtin_amdgcn_mfma_f32_16x16x32_bf16(ah[i], bl[j], acc[i][j], 0, 0, 0);
        acc[i][j] = __builtin_amdgcn_mfma_f32_16x16x32_bf16(al[i], bh[j], acc[i][j], 0, 0, 0);
      }
  }
  const int col = lane & 15, rowq = lane >> 4;
#pragma unroll
  for (int j = 0; j < 4; ++j) {
    int n = (nsB + j) * 16 + col;
    float bz = bias[n];
#pragma unroll
    for (int i = 0; i < 4; ++i) {
      int mbase = (mtB + i) * 16 + rowq * 4;
#pragma unroll
      for (int r = 0; r < 4; ++r)
        xg[(size_t)(mbase + r) * G4 + n] = acc[i][j][r] + bz;
    }
  }
}

// ---- diagonal LSTM step: blockIdx.z = layer, t = d - l ----
// grid (128 nt, 2 mp, 3 l), 512 thr = 8 waves (2x2 tiles x 2-way K-split).
// H frag layout: frag(l, parity, hi/lo) = H + ((l*2+p)*2+w)*HFRAG.
__global__ __launch_bounds__(512) void lstm_step_diag(
    unsigned short* __restrict__ H,
    const unsigned short* __restrict__ Whh_h0, const unsigned short* __restrict__ Whh_l0,
    const unsigned short* __restrict__ Whh_h1, const unsigned short* __restrict__ Whh_l1,
    const unsigned short* __restrict__ Whh_h2, const unsigned short* __restrict__ Whh_l2,
    const unsigned short* __restrict__ Wih_h1, const unsigned short* __restrict__ Wih_l1,
    const unsigned short* __restrict__ Wih_h2, const unsigned short* __restrict__ Wih_l2,
    const float* __restrict__ xg,     // layer-0 chunk [64, B, 4H]
    const float* __restrict__ bias,   // [3][4096]
    float* __restrict__ c_all,        // [3][B*H]
    float* __restrict__ hlast,        // [B*H]
    int d) {
  const int l = blockIdx.z;
  const int t = d - l;
  if (t < 0 || t >= TT) return;
  __shared__ float gbuf[2][32][40];
  const int tid = threadIdx.x, lane = tid & 63, w = tid >> 6;
  const int mw = w & 1, nw = (w >> 1) & 1, ks = w >> 2;
  const int nt = blockIdx.x, mp = blockIdx.y;
  const int mt = mp * 2 + mw, nsub = nt * 2 + nw;

  const unsigned short* whh_h = (l == 0) ? Whh_h0 : (l == 1) ? Whh_h1 : Whh_h2;
  const unsigned short* whh_l = (l == 0) ? Whh_l0 : (l == 1) ? Whh_l1 : Whh_l2;

  const size_t rec_off = ((size_t)(l * 2 + ((t + 1) & 1)) * 2) * HFRAG;  // [l][(t-1)&1]
  const short8* ra_hi = (const short8*)(H + rec_off) + (size_t)mt * 2048 + lane;
  const short8* ra_lo = (const short8*)(H + rec_off + HFRAG) + (size_t)mt * 2048 + lane;
  const short8* rb_hi = (const short8*)whh_h + (size_t)nsub * 2048 + lane;
  const short8* rb_lo = (const short8*)whh_l + (size_t)nsub * 2048 + lane;

  floatx4 acc = {0.f, 0.f, 0.f, 0.f};
  const int k0 = ks * 16;
  if (l == 0) {
#pragma unroll 4
    for (int kk = k0; kk < k0 + 16; ++kk) {
      short8 ahi = ra_hi[(size_t)kk * 64];
      short8 alo = ra_lo[(size_t)kk * 64];
      short8 bhi = rb_hi[(size_t)kk * 64];
      short8 blo = rb_lo[(size_t)kk * 64];
      acc = __builtin_amdgcn_mfma_f32_16x16x32_bf16(ahi, bhi, acc, 0, 0, 0);
      acc = __builtin_amdgcn_mfma_f32_16x16x32_bf16(ahi, blo, acc, 0, 0, 0);
      acc = __builtin_amdgcn_mfma_f32_16x16x32_bf16(alo, bhi, acc, 0, 0, 0);
    }
  } else {
    const unsigned short* wih_h = (l == 1) ? Wih_h1 : Wih_h2;
    const unsigned short* wih_l = (l == 1) ? Wih_l1 : Wih_l2;
    const size_t in_off = ((size_t)((l - 1) * 2 + (t & 1)) * 2) * HFRAG;  // [l-1][t&1]
    const short8* ia_hi = (const short8*)(H + in_off) + (size_t)mt * 2048 + lane;
    const short8* ia_lo = (const short8*)(H + in_off + HFRAG) + (size_t)mt * 2048 + lane;
    const short8* ib_hi = (const short8*)wih_h + (size_t)nsub * 2048 + lane;
    const short8* ib_lo = (const short8*)wih_l + (size_t)nsub * 2048 + lane;
#pragma unroll 2
    for (int kk = k0; kk < k0 + 16; ++kk) {
      short8 ahi = ra_hi[(size_t)kk * 64];
      short8 alo = ra_lo[(size_t)kk * 64];
      short8 bhi = rb_hi[(size_t)kk * 64];
      short8 blo = rb_lo[(size_t)kk * 64];
      short8 chi = ia_hi[(size_t)kk * 64];
      short8 clo = ia_lo[(size_t)kk * 64];
      short8 dhi = ib_hi[(size_t)kk * 64];
      short8 dlo = ib_lo[(size_t)kk * 64];
      acc = __builtin_amdgcn_mfma_f32_16x16x32_bf16(ahi, bhi, acc, 0, 0, 0);
      acc = __builtin_amdgcn_mfma_f32_16x16x32_bf16(ahi, blo, acc, 0, 0, 0);
      acc = __builtin_amdgcn_mfma_f32_16x16x32_bf16(alo, bhi, acc, 0, 0, 0);
      acc = __builtin_amdgcn_mfma_f32_16x16x32_bf16(chi, dhi, acc, 0, 0, 0);
      acc = __builtin_amdgcn_mfma_f32_16x16x32_bf16(chi, dlo, acc, 0, 0, 0);
      acc = __builtin_amdgcn_mfma_f32_16x16x32_bf16(clo, dhi, acc, 0, 0, 0);
    }
  }
  {
    int col = lane & 15, rowq = lane >> 4;
#pragma unroll
    for (int r = 0; r < 4; ++r)
      gbuf[ks][mw * 16 + rowq * 4 + r][nw * 16 + col] = acc[r];
  }
  __syncthreads();
  if (tid < 256) {
    int bl = tid >> 3, jl = tid & 7;
    int nlbase = (jl >> 2) * 16 + (jl & 3) * 4;
    float4 ga = *(float4*)&gbuf[0][bl][nlbase];
    float4 gb = *(float4*)&gbuf[1][bl][nlbase];
    int b = mp * 32 + bl;
    int j = nt * 8 + jl;
    float gi, gf, gg, go;
    if (l == 0) {
      int tl = t & (TCHUNK - 1);
      const float* xgp = xg + (size_t)(tl * BB + b) * G4 + j;
      gi = ga.x + gb.x + xgp[0];
      gf = ga.y + gb.y + xgp[HH];
      gg = ga.z + gb.z + xgp[2 * HH];
      go = ga.w + gb.w + xgp[3 * HH];
    } else {
      const float* bz = bias + (size_t)l * G4;
      gi = ga.x + gb.x + bz[j];
      gf = ga.y + gb.y + bz[HH + j];
      gg = ga.z + gb.z + bz[2 * HH + j];
      go = ga.w + gb.w + bz[3 * HH + j];
    }
    size_t hidx = (size_t)b * HH + j;
    float* c_cur = c_all + (size_t)l * (BB * HH);
    float cprev = c_cur[hidx];
    float ig = 1.f / (1.f + __expf(-gi));
    float fg = 1.f / (1.f + __expf(-gf));
    float g2 = tanhf(gg);
    float og = 1.f / (1.f + __expf(-go));
    float cn = fg * cprev + ig * g2;
    float hn = og * tanhf(cn);
    c_cur[hidx] = cn;
    // write h into A-frag layout, parity t&1
    unsigned short hb = bf16_rne(hn);
    unsigned short lb = bf16_rne(hn - bf16_to_f(hb));
    size_t slotN = (((size_t)(b >> 4) * 32 + (j >> 5)) * 64 +
                    ((j >> 3) & 3) * 16 + (b & 15)) * 8 + (j & 7);
    unsigned short* Nh = H + ((size_t)(l * 2 + (t & 1)) * 2) * HFRAG;
    Nh[slotN] = hb;
    Nh[HFRAG + slotN] = lb;
    if (l == 2 && t == TT - 1) hlast[hidx] = hn;
  }
}

// ---- final FC: out[b] = hlast[b,:] . fc_w + fc_b ----
__global__ __launch_bounds__(256) void final_fc(
    const float* __restrict__ hlast, const float* __restrict__ fc_w,
    const float* __restrict__ fc_b, float* __restrict__ out) {
  int b = blockIdx.x;
  const float* hrow = hlast + (size_t)b * HH;
  float s = 0.f;
  for (int j = threadIdx.x; j < HH; j += 256) s += hrow[j] * fc_w[j];
#pragma unroll
  for (int off = 32; off > 0; off >>= 1) s += __shfl_down(s, off, 64);
  __shared__ float wsum[4];
  int wv = threadIdx.x >> 6, ln = threadIdx.x & 63;
  if (ln == 0) wsum[wv] = s;
  __syncthreads();
  if (threadIdx.x == 0) out[b] = wsum[0] + wsum[1] + wsum[2] + wsum[3] + fc_b[0];
}

extern "C" void kernel_launch(void* const* d_in, const int* in_sizes, int n_in,
                              void* d_out, int out_size, void* d_ws,
                              size_t ws_size, hipStream_t stream) {
  const float* x = (const float*)d_in[0];
  const float* w_ih[3] = {(const float*)d_in[1], (const float*)d_in[5],
                          (const float*)d_in[9]};
  const float* w_hh[3] = {(const float*)d_in[2], (const float*)d_in[6],
                          (const float*)d_in[10]};
  const float* b_ih[3] = {(const float*)d_in[3], (const float*)d_in[7],
                          (const float*)d_in[11]};
  const float* b_hh[3] = {(const float*)d_in[4], (const float*)d_in[8],
                          (const float*)d_in[12]};
  const float* fc_w = (const float*)d_in[13];
  const float* fc_b = (const float*)d_in[14];
  float* out = (float*)d_out;

  char* ws = (char*)d_ws;
  size_t off = 0;
  auto alloc = [&](size_t bytes) {
    void* p = (void*)(ws + off);
    off += (bytes + 255) & ~(size_t)255;
    return p;
  };
  // recurrence weight B-frags (gate-interleaved)
  unsigned short *Whh_h[3], *Whh_l[3];
  for (int l = 0; l < 3; ++l) {
    Whh_h[l] = (unsigned short*)alloc((size_t)G4 * HH * 2);
    Whh_l[l] = (unsigned short*)alloc((size_t)G4 * HH * 2);
  }
  // input weight B-frags l=1,2 (gate-interleaved, same shape as w_hh)
  unsigned short *Wih_h[3], *Wih_l[3];
  for (int l = 1; l < 3; ++l) {
    Wih_h[l] = (unsigned short*)alloc((size_t)G4 * HH * 2);
    Wih_l[l] = (unsigned short*)alloc((size_t)G4 * HH * 2);
  }
  // layer-0 proj B-frags (direct rows, K=256)
  unsigned short* PB0h = (unsigned short*)alloc((size_t)G4 * DIN * 2);
  unsigned short* PB0l = (unsigned short*)alloc((size_t)G4 * DIN * 2);
  float* bias_all = (float*)alloc((size_t)3 * G4 * 4);
  // x proj A-frags
  unsigned short* PAxh = (unsigned short*)alloc((size_t)TT * BB * DIN * 2);
  unsigned short* PAxl = (unsigned short*)alloc((size_t)TT * BB * DIN * 2);
  // h frag buffers: [3 layers][2 parity][hi/lo] x 128 KB
  unsigned short* Hfr = (unsigned short*)alloc((size_t)3 * 2 * 2 * HFRAG * 2);
  float* c_all = (float*)alloc((size_t)3 * BB * HH * 4);
  float* hlast = (float*)alloc((size_t)BB * HH * 4);
  float* xg = (float*)alloc((size_t)TCHUNK * BB * G4 * 4);
  // total ~150 MB

  for (int l = 0; l < 3; ++l) {
    pack_w<<<2048, 256, 0, stream>>>(w_hh[l], Whh_h[l], Whh_l[l]);
    bias_add<<<16, 256, 0, stream>>>(b_ih[l], b_hh[l], bias_all + (size_t)l * G4);
  }
  pack_w<<<2048, 256, 0, stream>>>(w_ih[1], Wih_h[1], Wih_l[1]);
  pack_w<<<2048, 256, 0, stream>>>(w_ih[2], Wih_h[2], Wih_l[2]);
  pack_wih0<<<512, 256, 0, stream>>>(w_ih[0], PB0h, PB0l);
  pack_x<<<2048, 256, 0, stream>>>(x, PAxh, PAxl);

  // zero parity-1 h frags (read at t=0) and cell states
  for (int l = 0; l < 3; ++l)
    hipMemsetAsync(Hfr + ((size_t)(l * 2 + 1) * 2) * HFRAG, 0,
                   (size_t)2 * HFRAG * 2, stream);
  hipMemsetAsync(c_all, 0, (size_t)3 * BB * HH * 4, stream);

  for (int d = 0; d < TT + 2; ++d) {
    if ((d & (TCHUNK - 1)) == 0 && d < TT) {
      int c = d / TCHUNK;
      size_t aoff = (size_t)c * 256 * 8 * 512;  // 256 mt per chunk, NKK=8
      proj_mfma<<<dim3(32, 32), 256, 0, stream>>>(
          PAxh + aoff, PAxl + aoff, PB0h, PB0l, bias_all, xg, 8);
    }
    lstm_step_diag<<<dim3(128, 2, 3), 512, 0, stream>>>(
        Hfr, Whh_h[0], Whh_l[0], Whh_h[1], Whh_l[1], Whh_h[2], Whh_l[2],
        Wih_h[1], Wih_l[1], Wih_h[2], Wih_l[2], xg, bias_all, c_all, hlast, d);
  }
  final_fc<<<BB, 256, 0, stream>>>(hlast, fc_w, fc_b, out);
}